// Round 8
// baseline (20021.217 us; speedup 1.0000x reference)
//
#include <hip/hip_runtime.h>
#include <hip/hip_bf16.h>
#include <hip/hip_fp16.h>
#include <math.h>

#define NN 100000
#define NE 3200000
#define FIN 128
#define HD 64
#define NL 64
#define NC 47
#define RPW 4               // rows per wave (phase B / fallback)
#define WPB 4               // waves per block
#define RPB (RPW * WPB)     // rows per block = 16

#define NQ 4                // source quadrants: quad = src & 3
#define NSEG 4              // fallback dst-major CSR: key = dst*4 + quad
#define NKEY (NN * NQ)      // 400000 keys (both layouts)
#define KB ((NKEY + 1023) / 1024)   // scan blocks

#define PGRID 2048          // phase-A grid: ~8 blocks/CU x 256 CU
#define NTILE 3125          // 3125 * 32 rows = 100000

typedef float f32x4 __attribute__((ext_vector_type(4)));
typedef unsigned int u32x4 __attribute__((ext_vector_type(4)));

// ---------------- helpers ----------------

__device__ __forceinline__ float bf2f(unsigned short u) {
    union { unsigned int i; float f; } v; v.i = ((unsigned int)u) << 16; return v.f;
}
__device__ __forceinline__ unsigned short f2bf(float f) {
    __hip_bfloat16 h = __float2bfloat16(f);   // RNE
    return *reinterpret_cast<unsigned short*>(&h);
}
__device__ __forceinline__ float bflo(unsigned int u) {
    union { unsigned int i; float f; } v; v.i = u << 16; return v.f;
}
__device__ __forceinline__ float bfhi(unsigned int u) {
    union { unsigned int i; float f; } v; v.i = u & 0xFFFF0000u; return v.f;
}
__device__ __forceinline__ unsigned int pack2h(float a, float b) {
    __half ha = __float2half(a), hb = __float2half(b);
    unsigned short ua = *reinterpret_cast<unsigned short*>(&ha);
    unsigned short ub = *reinterpret_cast<unsigned short*>(&hb);
    return (unsigned int)ua | ((unsigned int)ub << 16);
}
__device__ __forceinline__ float h2f(unsigned short u) {
    __half h = *reinterpret_cast<__half*>(&u);
    return __half2float(h);
}
__device__ __forceinline__ float fin_at(const void* p, int isf32, size_t i) {
    return isf32 ? ((const float*)p)[i]
                 : __bfloat162float(((const __hip_bfloat16*)p)[i]);
}
__device__ __forceinline__ int edge_at(const void* p, int is64, size_t i) {
    return is64 ? (int)((const long long*)p)[i] : ((const int*)p)[i];
}

// ---------------- runtime dtype detection ----------------
// flags[0]: 1 = float inputs are fp32, 0 = bf16
// flags[1]: 1 = edge_index is int64, 0 = int32

__global__ void detect_kernel(const void* __restrict__ x, const void* __restrict__ eidx,
                              int* __restrict__ flags) {
    if (threadIdx.x == 0 && blockIdx.x == 0) {
        const unsigned short* u = (const unsigned short*)x;
        int sane = 0;
        for (int i = 0; i < 64; i++) {
            unsigned short v = u[2 * i];
            int e = (v >> 7) & 0xFF;
            if ((v & 0x7FFF) == 0 || (e >= 90 && e <= 141)) sane++;
        }
        flags[0] = (sane >= 48) ? 0 : 1;
        const int* e32 = (const int*)eidx;
        int nz = 0;
        for (int i = 0; i < 64; i++) if (e32[2 * i + 1] != 0) nz++;
        flags[1] = (nz == 0) ? 1 : 0;
    }
}

// ---------------- CSR build ----------------
// big=1: key = quad*NN + dst   (quad-major, for XCD-partitioned two-phase)
// big=0: key = dst*4 + quad    (dst-major, for fallback flat gather)

__global__ void key_count(const void* __restrict__ eidx, const int* __restrict__ flags,
                          int* __restrict__ cnt, int big) {
    int e = blockIdx.x * blockDim.x + threadIdx.x;
    if (e < NE) {
        int is64 = flags[1];
        int s = edge_at(eidx, is64, (size_t)e);
        int d = edge_at(eidx, is64, (size_t)NE + e);
        int q = s & 3;
        int key = big ? (q * NN + d) : (d * 4 + q);
        atomicAdd(&cnt[key], 1);
    }
}

__global__ __launch_bounds__(1024) void scan_reduce(const int* __restrict__ cnt,
                                                    int* __restrict__ bsum) {
    __shared__ int lds[1024];
    int tid = threadIdx.x;
    int i = blockIdx.x * 1024 + tid;
    lds[tid] = (i < NKEY) ? cnt[i] : 0;
    __syncthreads();
    for (int off = 512; off > 0; off >>= 1) {
        if (tid < off) lds[tid] += lds[tid + off];
        __syncthreads();
    }
    if (tid == 0) bsum[blockIdx.x] = lds[0];
}

__global__ __launch_bounds__(1024) void scan_mid(int* __restrict__ bsum, int* __restrict__ total_out) {
    __shared__ int lds[1024];
    __shared__ int base_s;
    int tid = threadIdx.x;
    if (tid == 0) base_s = 0;
    __syncthreads();
    for (int chunk = 0; chunk < KB; chunk += 1024) {
        int i = chunk + tid;
        int v = (i < KB) ? bsum[i] : 0;
        lds[tid] = v;
        __syncthreads();
        for (int off = 1; off < 1024; off <<= 1) {
            int t = (tid >= off) ? lds[tid - off] : 0;
            __syncthreads();
            lds[tid] += t;
            __syncthreads();
        }
        int incl = lds[tid];
        int base = base_s;
        if (i < KB) bsum[i] = base + incl - v;
        __syncthreads();
        if (tid == 1023) base_s = base + incl;
        __syncthreads();
    }
    if (tid == 0) *total_out = base_s;   // == NE
}

__global__ __launch_bounds__(1024) void scan_final(const int* __restrict__ cnt,
                                                   const int* __restrict__ bsum,
                                                   int* __restrict__ keyptr) {
    __shared__ int lds[1024];
    int tid = threadIdx.x;
    int i = blockIdx.x * 1024 + tid;
    int v = (i < NKEY) ? cnt[i] : 0;
    lds[tid] = v;
    __syncthreads();
    for (int off = 1; off < 1024; off <<= 1) {
        int t = (tid >= off) ? lds[tid - off] : 0;
        __syncthreads();
        lds[tid] += t;
        __syncthreads();
    }
    if (i < NKEY) keyptr[i] = bsum[blockIdx.x] + lds[tid] - v;
}

__global__ void dinv_kernel(const int* __restrict__ keyptr, float* __restrict__ dinv, int big) {
    int i = blockIdx.x * blockDim.x + threadIdx.x;
    if (i < NN) {
        int deg;
        if (big) {
            deg = 0;
            #pragma unroll
            for (int q = 0; q < NQ; q++)
                deg += keyptr[q * NN + i + 1] - keyptr[q * NN + i];
        } else {
            deg = keyptr[(i + 1) * NSEG] - keyptr[i * NSEG];
        }
        dinv[i] = rsqrtf(1.0f + (float)deg);   // +1 self-loop
    }
}

__global__ void scatter_kernel(const void* __restrict__ eidx, const int* __restrict__ flags,
                               const int* __restrict__ keyptr, int* __restrict__ fill,
                               int* __restrict__ col, int big) {
    int e = blockIdx.x * blockDim.x + threadIdx.x;
    if (e < NE) {
        int is64 = flags[1];
        int s = edge_at(eidx, is64, (size_t)e);
        int d = edge_at(eidx, is64, (size_t)NE + e);
        int q = s & 3;
        int key = big ? (q * NN + d) : (d * 4 + q);
        int pos = keyptr[key] + atomicAdd(&fill[key], 1);
        col[pos] = s;
    }
}

// ---------------- x0 = relu(x @ W1 + b1); x0 bf16, g0 = dinv*x0 bf16 ----------------

__global__ __launch_bounds__(256) void x0_kernel(const void* __restrict__ x,
                                                 const void* __restrict__ W1,
                                                 const void* __restrict__ b1,
                                                 const int* __restrict__ flags,
                                                 const float* __restrict__ dinv,
                                                 unsigned short* __restrict__ x0b,
                                                 unsigned short* __restrict__ g0) {
    __shared__ float lw[FIN * HD];  // 32 KiB
    int isf = flags[0];
    int tid = threadIdx.x;
    for (int i = tid; i < FIN * HD; i += 256) lw[i] = fin_at(W1, isf, i);
    __syncthreads();
    int wave = tid >> 6, lane = tid & 63;
    int row0 = blockIdx.x * RPB + wave * RPW;
    if (row0 >= NN) return;
    unsigned int pa01, pa23, pb01, pb23;
    {
        unsigned short a0 = f2bf(fin_at(x, isf, (size_t)(row0 + 0) * FIN + lane));
        unsigned short a1 = f2bf(fin_at(x, isf, (size_t)(row0 + 1) * FIN + lane));
        unsigned short a2 = f2bf(fin_at(x, isf, (size_t)(row0 + 2) * FIN + lane));
        unsigned short a3 = f2bf(fin_at(x, isf, (size_t)(row0 + 3) * FIN + lane));
        unsigned short c0 = f2bf(fin_at(x, isf, (size_t)(row0 + 0) * FIN + 64 + lane));
        unsigned short c1 = f2bf(fin_at(x, isf, (size_t)(row0 + 1) * FIN + 64 + lane));
        unsigned short c2 = f2bf(fin_at(x, isf, (size_t)(row0 + 2) * FIN + 64 + lane));
        unsigned short c3 = f2bf(fin_at(x, isf, (size_t)(row0 + 3) * FIN + 64 + lane));
        pa01 = ((unsigned int)a0 << 16) | a1;  pa23 = ((unsigned int)a2 << 16) | a3;
        pb01 = ((unsigned int)c0 << 16) | c1;  pb23 = ((unsigned int)c2 << 16) | c3;
    }
    float bias = fin_at(b1, isf, lane);
    float d0 = bias, d1 = bias, d2 = bias, d3 = bias;
    #pragma unroll 8
    for (int k = 0; k < 64; k++) {
        float w = lw[k * HD + lane];
        unsigned int b01 = __shfl(pa01, k, 64);
        unsigned int b23 = __shfl(pa23, k, 64);
        union { unsigned int i; float f; } f0, f1, f2, f3;
        f0.i = b01 & 0xFFFF0000u; f1.i = b01 << 16;
        f2.i = b23 & 0xFFFF0000u; f3.i = b23 << 16;
        d0 += f0.f * w; d1 += f1.f * w; d2 += f2.f * w; d3 += f3.f * w;
    }
    #pragma unroll 8
    for (int k = 0; k < 64; k++) {
        float w = lw[(64 + k) * HD + lane];
        unsigned int b01 = __shfl(pb01, k, 64);
        unsigned int b23 = __shfl(pb23, k, 64);
        union { unsigned int i; float f; } f0, f1, f2, f3;
        f0.i = b01 & 0xFFFF0000u; f1.i = b01 << 16;
        f2.i = b23 & 0xFFFF0000u; f3.i = b23 << 16;
        d0 += f0.f * w; d1 += f1.f * w; d2 += f2.f * w; d3 += f3.f * w;
    }
    float dd[RPW] = {d0, d1, d2, d3};
    #pragma unroll
    for (int r = 0; r < RPW; r++) {
        int row = row0 + r;
        if (row >= NN) continue;
        float v = fmaxf(dd[r], 0.0f);
        x0b[(size_t)row * HD + lane] = f2bf(v);
        g0[(size_t)row * HD + lane] = f2bf(dinv[row] * v);
    }
}

// ---------------- PHASE A: XCD-partitioned partial SpMM ----------------
// Quad selection via the REAL hardware XCD id (s_getreg HW_REG_XCC_ID, HW-
// verified on gfx950) -- no scheduler-mapping assumption. Blocks on XCD k
// process quad k&3, pulling tiles from a per-quad atomic counter: all blocks
// of a quad sweep tiles IN ORDER, so col/keyptr reads are temporally local
// (cached loads, small instantaneous footprint) and the XCD's L2 holds its
// quad's 3.2-MB g window. After finishing its own quad a block STEALS from
// the other quads' counters -> completeness guaranteed for any scheduler.
// Self-loop folded in; fp16 partials via one 16-B NT store.

__global__ __launch_bounds__(256, 8) void spmm_partial(const int* __restrict__ keyptr,
                                                       const int* __restrict__ colq,
                                                       const unsigned short* __restrict__ g_in,
                                                       unsigned short* __restrict__ part,
                                                       int* __restrict__ qcnt) {
    unsigned int xcc;
    asm volatile("s_getreg_b32 %0, hwreg(HW_REG_XCC_ID)" : "=s"(xcc));
    int myq = (int)(xcc & 3);
    __shared__ int tile_s;
    int tid = threadIdx.x;
    int wave = tid >> 6, lane = tid & 63;
    int grp = lane >> 3, li = lane & 7;
    const char* gb = (const char*)g_in;

    for (int qi = 0; qi < NQ; qi++) {
        int quad = (myq + qi) & 3;
        while (true) {
            __syncthreads();
            if (tid == 0) tile_s = atomicAdd(&qcnt[quad], 1);
            __syncthreads();
            int tile = tile_s;
            if (tile >= NTILE) break;

            int row = tile * 32 + wave * 8 + grp;      // 3125 * 32 = 100000 exactly
            size_t kbase = (size_t)quad * NN + row;
            int jbeg = keyptr[kbase];
            int jend = keyptr[kbase + 1];
            int cnt = jend - jbeg;

            float a0 = 0.0f, a1 = 0.0f, a2 = 0.0f, a3 = 0.0f;
            float a4 = 0.0f, a5 = 0.0f, a6 = 0.0f, a7 = 0.0f;

            for (int base = 0; base < cnt; base += 8) {
                int idx = jbeg + base + li;
                int cv = colq[idx < jend ? idx : (jend - 1)];   // cnt>0 inside loop
                int rem = cnt - base;
                #pragma unroll
                for (int k = 0; k < 8; k++) {
                    if (k < rem) {   // per-group exec mask; shfl src shares predicate
                        int ck = __shfl(cv, (lane & 56) + k, 64);
                        uint4 u = *reinterpret_cast<const uint4*>(
                            gb + (((size_t)ck) << 7) + (li << 4));
                        a0 += bflo(u.x); a1 += bfhi(u.x);
                        a2 += bflo(u.y); a3 += bfhi(u.y);
                        a4 += bflo(u.z); a5 += bfhi(u.z);
                        a6 += bflo(u.w); a7 += bfhi(u.w);
                    }
                }
            }

            // fold self-loop into this row's own quad (row is in our g window)
            if (quad == (row & 3)) {
                uint4 u = *reinterpret_cast<const uint4*>(
                    gb + (((size_t)row) << 7) + (li << 4));
                a0 += bflo(u.x); a1 += bfhi(u.x);
                a2 += bflo(u.y); a3 += bfhi(u.y);
                a4 += bflo(u.z); a5 += bfhi(u.z);
                a6 += bflo(u.w); a7 += bfhi(u.w);
            }

            u32x4 v = {pack2h(a0, a1), pack2h(a2, a3), pack2h(a4, a5), pack2h(a6, a7)};
            unsigned short* pp = part + kbase * HD + (li << 3);
            __builtin_nontemporal_store(v, reinterpret_cast<u32x4*>(pp));
        }
    }
}

// ---------------- PHASE B: combine partials + residual mix + dense + relu ----------------

__global__ __launch_bounds__(256, 8) void layer_combine(const unsigned short* __restrict__ part,
                                                        const float* __restrict__ dinv,
                                                        const unsigned short* __restrict__ x0b,
                                                        unsigned short* __restrict__ g_out,
                                                        const void* __restrict__ convW, int layer,
                                                        const int* __restrict__ flags, float beta) {
    __shared__ float lw[HD * HD];  // 16 KiB
    int isf = flags[0];
    size_t wbase = (size_t)layer * HD * HD;
    int tid = threadIdx.x;
    for (int i = tid; i < HD * HD; i += 256) lw[i] = fin_at(convW, isf, wbase + i);
    __syncthreads();

    int wave = __builtin_amdgcn_readfirstlane(tid >> 6);
    int lane = tid & 63;
    int row0 = blockIdx.x * RPB + wave * RPW;

    float sacc[RPW];
    float dsc[RPW];
    #pragma unroll
    for (int r = 0; r < RPW; r++) {
        int row = row0 + r;
        if (row >= NN) { sacc[r] = 0.0f; dsc[r] = 1.0f; continue; }
        float a = 0.0f;
        #pragma unroll
        for (int q = 0; q < NQ; q++) {
            unsigned short u = __builtin_nontemporal_load(
                part + ((size_t)q * NN + row) * HD + lane);
            a += h2f(u);
        }
        float di = dinv[row];
        dsc[r] = di;
        sacc[r] = 0.9f * (di * a) + 0.1f * bf2f(x0b[((size_t)row << 6) + lane]);
    }

    // dense: d = s @ Wl ; s packed 2-rows-per-dword bf16, broadcast via shfl
    unsigned int p01 = ((unsigned int)f2bf(sacc[0]) << 16) | f2bf(sacc[1]);
    unsigned int p23 = ((unsigned int)f2bf(sacc[2]) << 16) | f2bf(sacc[3]);
    float d0 = 0.0f, d1 = 0.0f, d2 = 0.0f, d3 = 0.0f;
    #pragma unroll 8
    for (int k = 0; k < 64; k++) {
        float w = lw[k * HD + lane];
        unsigned int b01 = __shfl(p01, k, 64);
        unsigned int b23 = __shfl(p23, k, 64);
        union { unsigned int i; float f; } f0, f1, f2, f3;
        f0.i = b01 & 0xFFFF0000u; f1.i = b01 << 16;
        f2.i = b23 & 0xFFFF0000u; f3.i = b23 << 16;
        d0 += f0.f * w; d1 += f1.f * w;
        d2 += f2.f * w; d3 += f3.f * w;
    }

    float dd[RPW] = {d0, d1, d2, d3};
    float omb = 1.0f - beta;
    #pragma unroll
    for (int r = 0; r < RPW; r++) {
        int row = row0 + r;
        if (row >= NN) continue;
        float res = omb * sacc[r] + beta * dd[r];
        g_out[((size_t)row << 6) + lane] = f2bf(dsc[r] * fmaxf(res, 0.0f));
    }
}

// ---------------- FALLBACK: round-3 fused layer (dst-major CSR, NSEG=4) ----------------

__global__ __launch_bounds__(256, 8) void layer_fused(const int* __restrict__ keyptr,
                                                      const int* __restrict__ col,
                                                      const float* __restrict__ dinv,
                                                      const unsigned short* __restrict__ g_in,
                                                      const unsigned short* __restrict__ x0b,
                                                      unsigned short* __restrict__ g_out,
                                                      const void* __restrict__ convW, int layer,
                                                      const int* __restrict__ flags, float beta) {
    __shared__ float lw[HD * HD];  // 16 KiB
    int isf = flags[0];
    size_t wbase = (size_t)layer * HD * HD;
    int tid = threadIdx.x;
    for (int i = tid; i < HD * HD; i += 256) lw[i] = fin_at(convW, isf, wbase + i);
    __syncthreads();

    int wave = __builtin_amdgcn_readfirstlane(tid >> 6);
    int lane = tid & 63;
    int eslot = lane >> 3;            // edge slot 0..7 within a group
    int sbyte = (lane & 7) << 4;      // byte offset of this lane's 16-B slice
    const char* gb = (const char*)g_in;

    int row0 = blockIdx.x * RPB + wave * RPW;

    float sacc[RPW];
    float dsc[RPW];
    #pragma unroll
    for (int r = 0; r < RPW; r++) {
        int row = row0 + r;
        if (row >= NN) { sacc[r] = 0.0f; dsc[r] = 1.0f; continue; }
        int start = keyptr[row * NSEG];
        int end   = keyptr[(row + 1) * NSEG];

        float a0 = 0.0f, a1 = 0.0f, a2 = 0.0f, a3 = 0.0f;
        float a4 = 0.0f, a5 = 0.0f, a6 = 0.0f, a7 = 0.0f;

        for (int j = start; j < end; j += 32) {
            int le = end - 1;
            int i0 = j + eslot, i1 = i0 + 8, i2 = i0 + 16, i3 = i0 + 24;
            int c0 = col[i0 < end ? i0 : le];
            int c1 = col[i1 < end ? i1 : le];
            int c2 = col[i2 < end ? i2 : le];
            int c3 = col[i3 < end ? i3 : le];
            uint4 u0 = *reinterpret_cast<const uint4*>(gb + (((size_t)c0) << 7) + sbyte);
            uint4 u1 = *reinterpret_cast<const uint4*>(gb + (((size_t)c1) << 7) + sbyte);
            uint4 u2 = *reinterpret_cast<const uint4*>(gb + (((size_t)c2) << 7) + sbyte);
            uint4 u3 = *reinterpret_cast<const uint4*>(gb + (((size_t)c3) << 7) + sbyte);
            float m0 = (i0 < end) ? 1.0f : 0.0f;
            float m1 = (i1 < end) ? 1.0f : 0.0f;
            float m2 = (i2 < end) ? 1.0f : 0.0f;
            float m3 = (i3 < end) ? 1.0f : 0.0f;
            a0 = fmaf(m0, bflo(u0.x), a0); a1 = fmaf(m0, bfhi(u0.x), a1);
            a2 = fmaf(m0, bflo(u0.y), a2); a3 = fmaf(m0, bfhi(u0.y), a3);
            a4 = fmaf(m0, bflo(u0.z), a4); a5 = fmaf(m0, bfhi(u0.z), a5);
            a6 = fmaf(m0, bflo(u0.w), a6); a7 = fmaf(m0, bfhi(u0.w), a7);
            a0 = fmaf(m1, bflo(u1.x), a0); a1 = fmaf(m1, bfhi(u1.x), a1);
            a2 = fmaf(m1, bflo(u1.y), a2); a3 = fmaf(m1, bfhi(u1.y), a3);
            a4 = fmaf(m1, bflo(u1.z), a4); a5 = fmaf(m1, bfhi(u1.z), a5);
            a6 = fmaf(m1, bflo(u1.w), a6); a7 = fmaf(m1, bfhi(u1.w), a7);
            a0 = fmaf(m2, bflo(u2.x), a0); a1 = fmaf(m2, bfhi(u2.x), a1);
            a2 = fmaf(m2, bflo(u2.y), a2); a3 = fmaf(m2, bfhi(u2.y), a3);
            a4 = fmaf(m2, bflo(u2.z), a4); a5 = fmaf(m2, bfhi(u2.z), a5);
            a6 = fmaf(m2, bflo(u2.w), a6); a7 = fmaf(m2, bfhi(u2.w), a7);
            a0 = fmaf(m3, bflo(u3.x), a0); a1 = fmaf(m3, bfhi(u3.x), a1);
            a2 = fmaf(m3, bflo(u3.y), a2); a3 = fmaf(m3, bfhi(u3.y), a3);
            a4 = fmaf(m3, bflo(u3.z), a4); a5 = fmaf(m3, bfhi(u3.z), a5);
            a6 = fmaf(m3, bflo(u3.w), a6); a7 = fmaf(m3, bfhi(u3.w), a7);
        }

        a0 += __shfl_xor(a0, 8, 64); a0 += __shfl_xor(a0, 16, 64); a0 += __shfl_xor(a0, 32, 64);
        a1 += __shfl_xor(a1, 8, 64); a1 += __shfl_xor(a1, 16, 64); a1 += __shfl_xor(a1, 32, 64);
        a2 += __shfl_xor(a2, 8, 64); a2 += __shfl_xor(a2, 16, 64); a2 += __shfl_xor(a2, 32, 64);
        a3 += __shfl_xor(a3, 8, 64); a3 += __shfl_xor(a3, 16, 64); a3 += __shfl_xor(a3, 32, 64);
        a4 += __shfl_xor(a4, 8, 64); a4 += __shfl_xor(a4, 16, 64); a4 += __shfl_xor(a4, 32, 64);
        a5 += __shfl_xor(a5, 8, 64); a5 += __shfl_xor(a5, 16, 64); a5 += __shfl_xor(a5, 32, 64);
        a6 += __shfl_xor(a6, 8, 64); a6 += __shfl_xor(a6, 16, 64); a6 += __shfl_xor(a6, 32, 64);
        a7 += __shfl_xor(a7, 8, 64); a7 += __shfl_xor(a7, 16, 64); a7 += __shfl_xor(a7, 32, 64);

        int srcl = lane >> 3;
        float t0 = __shfl(a0, srcl, 64);
        float t1 = __shfl(a1, srcl, 64);
        float t2 = __shfl(a2, srcl, 64);
        float t3 = __shfl(a3, srcl, 64);
        float t4 = __shfl(a4, srcl, 64);
        float t5 = __shfl(a5, srcl, 64);
        float t6 = __shfl(a6, srcl, 64);
        float t7 = __shfl(a7, srcl, 64);
        int b0 = lane & 1, b1 = (lane >> 1) & 1, b2 = (lane >> 2) & 1;
        float s01 = b0 ? t1 : t0, s23 = b0 ? t3 : t2;
        float s45 = b0 ? t5 : t4, s67 = b0 ? t7 : t6;
        float sA = b1 ? s23 : s01, sB = b1 ? s67 : s45;
        float gsum = b2 ? sB : sA;

        float a = gsum + bf2f(g_in[((size_t)row << 6) + lane]);
        float di = dinv[row];
        dsc[r] = di;
        sacc[r] = 0.9f * (di * a) + 0.1f * bf2f(x0b[((size_t)row << 6) + lane]);
    }

    unsigned int p01 = ((unsigned int)f2bf(sacc[0]) << 16) | f2bf(sacc[1]);
    unsigned int p23 = ((unsigned int)f2bf(sacc[2]) << 16) | f2bf(sacc[3]);
    float d0 = 0.0f, d1 = 0.0f, d2 = 0.0f, d3 = 0.0f;
    #pragma unroll 8
    for (int k = 0; k < 64; k++) {
        float w = lw[k * HD + lane];
        unsigned int b01 = __shfl(p01, k, 64);
        unsigned int b23 = __shfl(p23, k, 64);
        union { unsigned int i; float f; } f0, f1, f2, f3;
        f0.i = b01 & 0xFFFF0000u; f1.i = b01 << 16;
        f2.i = b23 & 0xFFFF0000u; f3.i = b23 << 16;
        d0 += f0.f * w; d1 += f1.f * w;
        d2 += f2.f * w; d3 += f3.f * w;
    }

    float dd[RPW] = {d0, d1, d2, d3};
    float omb = 1.0f - beta;
    #pragma unroll
    for (int r = 0; r < RPW; r++) {
        int row = row0 + r;
        if (row >= NN) continue;
        float res = omb * sacc[r] + beta * dd[r];
        g_out[((size_t)row << 6) + lane] = f2bf(dsc[r] * fmaxf(res, 0.0f));
    }
}

// ---------------- out = log_softmax(h @ W2 + b2), h = g/dinv ----------------

__global__ __launch_bounds__(256) void out_kernel(const unsigned short* __restrict__ g,
                                                  const float* __restrict__ dinv,
                                                  const void* __restrict__ W2,
                                                  const void* __restrict__ b2,
                                                  const int* __restrict__ flags,
                                                  void* __restrict__ out) {
    __shared__ float lw[HD * 64];
    int isf = flags[0];
    int tid = threadIdx.x;
    for (int i = tid; i < HD * 64; i += 256) {
        int k = i >> 6, j = i & 63;
        lw[i] = (j < NC) ? fin_at(W2, isf, (size_t)k * NC + j) : 0.0f;
    }
    __syncthreads();
    int row = blockIdx.x * 4 + (tid >> 6);
    int lane = tid & 63;
    if (row >= NN) return;
    float hv = bf2f(g[(size_t)row * HD + lane]) / dinv[row];
    float acc = (lane < NC) ? fin_at(b2, isf, lane) : 0.0f;
    #pragma unroll 8
    for (int k = 0; k < 64; k++) {
        float hk = __shfl(hv, k, 64);
        acc += hk * lw[k * 64 + lane];
    }
    float mv = (lane < NC) ? acc : -1e30f;
    for (int off = 32; off > 0; off >>= 1) mv = fmaxf(mv, __shfl_xor(mv, off, 64));
    float ex = (lane < NC) ? expf(acc - mv) : 0.0f;
    float se = ex;
    for (int off = 32; off > 0; off >>= 1) se += __shfl_xor(se, off, 64);
    float res = acc - mv - logf(se);
    if (lane < NC) {
        size_t oi = (size_t)row * NC + lane;
        if (isf) ((float*)out)[oi] = res;
        else     ((__hip_bfloat16*)out)[oi] = __float2bfloat16(res);
    }
}

// ---------------- host ----------------

static inline size_t align256(size_t x) { return (x + 255) & ~(size_t)255; }

extern "C" void kernel_launch(void* const* d_in, const int* in_sizes, int n_in,
                              void* d_out, int out_size, void* d_ws, size_t ws_size,
                              hipStream_t stream) {
    const void* x     = d_in[0];
    const void* eidx  = d_in[1];
    const void* W1    = d_in[2];
    const void* b1    = d_in[3];
    const void* convW = d_in[4];
    const void* W2    = d_in[5];
    const void* b2    = d_in[6];

    char* p = (char*)d_ws;
    size_t off = 0;
    auto alloc = [&](size_t bytes) { void* r = p + off; off += align256(bytes); return r; };
    int*            flags   = (int*)alloc(256);
    int*            cnt     = (int*)alloc((size_t)NKEY * 4);
    int*            fill    = (int*)alloc((size_t)NKEY * 4);
    int*            keyptr  = (int*)alloc((size_t)(NKEY + 1) * 4);
    int*            bsum    = (int*)alloc((size_t)KB * 4);
    float*          dinv    = (float*)alloc((size_t)NN * 4);
    int*            col     = (int*)alloc((size_t)NE * 4);
    unsigned short* x0b     = (unsigned short*)alloc((size_t)NN * HD * 2);
    unsigned short* hA      = (unsigned short*)alloc((size_t)NN * HD * 2);
    unsigned short* hB      = (unsigned short*)alloc((size_t)NN * HD * 2);
    int*            qcnt    = (int*)alloc((size_t)NL * NQ * 4);   // per-layer tile counters

    size_t part_bytes = (size_t)NQ * NN * HD * 2;   // 51.2 MB fp16 partials
    int big = (off + part_bytes) <= ws_size;
    unsigned short* part = (unsigned short*)(p + off);   // only used if big

    detect_kernel<<<1, 64, 0, stream>>>(x, eidx, flags);

    hipMemsetAsync(cnt, 0, (size_t)NKEY * 4, stream);
    hipMemsetAsync(fill, 0, (size_t)NKEY * 4, stream);
    hipMemsetAsync(qcnt, 0, (size_t)NL * NQ * 4, stream);
    key_count<<<(NE + 255) / 256, 256, 0, stream>>>(eidx, flags, cnt, big);
    scan_reduce<<<KB, 1024, 0, stream>>>(cnt, bsum);
    scan_mid<<<1, 1024, 0, stream>>>(bsum, keyptr + NKEY);
    scan_final<<<KB, 1024, 0, stream>>>(cnt, bsum, keyptr);
    dinv_kernel<<<(NN + 255) / 256, 256, 0, stream>>>(keyptr, dinv, big);
    scatter_kernel<<<(NE + 255) / 256, 256, 0, stream>>>(eidx, flags, keyptr, fill, col, big);

    int fb = (NN + RPB - 1) / RPB;  // 6250 blocks
    x0_kernel<<<fb, 256, 0, stream>>>(x, W1, b1, flags, dinv, x0b, hA);

    unsigned short* gin = hA;
    unsigned short* gout = hB;
    for (int l = 0; l < NL; l++) {
        float beta = logf(0.5f / (float)(l + 1) + 1.0f);
        if (big) {
            spmm_partial<<<PGRID, 256, 0, stream>>>(keyptr, col, gin, part, qcnt + l * NQ);
            layer_combine<<<fb, 256, 0, stream>>>(part, dinv, x0b, gout,
                                                  convW, l, flags, beta);
        } else {
            layer_fused<<<fb, 256, 0, stream>>>(keyptr, col, dinv, gin, x0b, gout,
                                                convW, l, flags, beta);
        }
        unsigned short* t = gin; gin = gout; gout = t;
    }
    out_kernel<<<(NN + 3) / 4, 256, 0, stream>>>(gin, dinv, W2, b2, flags, (void*)d_out);
}

// Round 9
// 11225.179 us; speedup vs baseline: 1.7836x; 1.7836x over previous
//
#include <hip/hip_runtime.h>
#include <hip/hip_bf16.h>
#include <hip/hip_fp16.h>
#include <math.h>

#define NN 100000
#define NE 3200000
#define FIN 128
#define HD 64
#define NL 64
#define NC 47
#define RPW 4               // rows per wave (phase B / fallback)
#define WPB 4               // waves per block
#define RPB (RPW * WPB)     // rows per block = 16

#define NQ 4                // source quadrants: quad = src & 3
#define NSEG 4              // fallback dst-major CSR: key = dst*4 + quad
#define NKEY (NN * NQ)      // 400000 keys (both layouts)
#define KB ((NKEY + 1023) / 1024)   // scan blocks

#define PGRID 2048          // phase-A grid: 8 blocks/CU x 256 CU
#define CHROWS 32           // rows per dispensed chunk
#define NCHQ (NN / CHROWS)  // 3125 chunks per quad (exact)
#define QPAD 32             // ints between per-quad counters (128-B separation)

typedef float f32x4 __attribute__((ext_vector_type(4)));
typedef unsigned int u32x4 __attribute__((ext_vector_type(4)));

// ---------------- helpers ----------------

__device__ __forceinline__ float bf2f(unsigned short u) {
    union { unsigned int i; float f; } v; v.i = ((unsigned int)u) << 16; return v.f;
}
__device__ __forceinline__ unsigned short f2bf(float f) {
    __hip_bfloat16 h = __float2bfloat16(f);   // RNE
    return *reinterpret_cast<unsigned short*>(&h);
}
__device__ __forceinline__ float bflo(unsigned int u) {
    union { unsigned int i; float f; } v; v.i = u << 16; return v.f;
}
__device__ __forceinline__ float bfhi(unsigned int u) {
    union { unsigned int i; float f; } v; v.i = u & 0xFFFF0000u; return v.f;
}
__device__ __forceinline__ unsigned int pack2h(float a, float b) {
    __half ha = __float2half(a), hb = __float2half(b);
    unsigned short ua = *reinterpret_cast<unsigned short*>(&ha);
    unsigned short ub = *reinterpret_cast<unsigned short*>(&hb);
    return (unsigned int)ua | ((unsigned int)ub << 16);
}
__device__ __forceinline__ float h2f(unsigned short u) {
    __half h = *reinterpret_cast<__half*>(&u);
    return __half2float(h);
}
__device__ __forceinline__ float fin_at(const void* p, int isf32, size_t i) {
    return isf32 ? ((const float*)p)[i]
                 : __bfloat162float(((const __hip_bfloat16*)p)[i]);
}
__device__ __forceinline__ int edge_at(const void* p, int is64, size_t i) {
    return is64 ? (int)((const long long*)p)[i] : ((const int*)p)[i];
}

// ---------------- runtime dtype detection ----------------

__global__ void detect_kernel(const void* __restrict__ x, const void* __restrict__ eidx,
                              int* __restrict__ flags) {
    if (threadIdx.x == 0 && blockIdx.x == 0) {
        const unsigned short* u = (const unsigned short*)x;
        int sane = 0;
        for (int i = 0; i < 64; i++) {
            unsigned short v = u[2 * i];
            int e = (v >> 7) & 0xFF;
            if ((v & 0x7FFF) == 0 || (e >= 90 && e <= 141)) sane++;
        }
        flags[0] = (sane >= 48) ? 0 : 1;
        const int* e32 = (const int*)eidx;
        int nz = 0;
        for (int i = 0; i < 64; i++) if (e32[2 * i + 1] != 0) nz++;
        flags[1] = (nz == 0) ? 1 : 0;
    }
}

// ---------------- CSR build ----------------
// big=1: key = quad*NN + dst   (quad-major, XCD-partitioned two-phase)
// big=0: key = dst*4 + quad    (dst-major, fallback flat gather)

__global__ void key_count(const void* __restrict__ eidx, const int* __restrict__ flags,
                          int* __restrict__ cnt, int big) {
    int e = blockIdx.x * blockDim.x + threadIdx.x;
    if (e < NE) {
        int is64 = flags[1];
        int s = edge_at(eidx, is64, (size_t)e);
        int d = edge_at(eidx, is64, (size_t)NE + e);
        int q = s & 3;
        int key = big ? (q * NN + d) : (d * 4 + q);
        atomicAdd(&cnt[key], 1);
    }
}

__global__ __launch_bounds__(1024) void scan_reduce(const int* __restrict__ cnt,
                                                    int* __restrict__ bsum) {
    __shared__ int lds[1024];
    int tid = threadIdx.x;
    int i = blockIdx.x * 1024 + tid;
    lds[tid] = (i < NKEY) ? cnt[i] : 0;
    __syncthreads();
    for (int off = 512; off > 0; off >>= 1) {
        if (tid < off) lds[tid] += lds[tid + off];
        __syncthreads();
    }
    if (tid == 0) bsum[blockIdx.x] = lds[0];
}

__global__ __launch_bounds__(1024) void scan_mid(int* __restrict__ bsum, int* __restrict__ total_out) {
    __shared__ int lds[1024];
    __shared__ int base_s;
    int tid = threadIdx.x;
    if (tid == 0) base_s = 0;
    __syncthreads();
    for (int chunk = 0; chunk < KB; chunk += 1024) {
        int i = chunk + tid;
        int v = (i < KB) ? bsum[i] : 0;
        lds[tid] = v;
        __syncthreads();
        for (int off = 1; off < 1024; off <<= 1) {
            int t = (tid >= off) ? lds[tid - off] : 0;
            __syncthreads();
            lds[tid] += t;
            __syncthreads();
        }
        int incl = lds[tid];
        int base = base_s;
        if (i < KB) bsum[i] = base + incl - v;
        __syncthreads();
        if (tid == 1023) base_s = base + incl;
        __syncthreads();
    }
    if (tid == 0) *total_out = base_s;   // == NE
}

__global__ __launch_bounds__(1024) void scan_final(const int* __restrict__ cnt,
                                                   const int* __restrict__ bsum,
                                                   int* __restrict__ keyptr) {
    __shared__ int lds[1024];
    int tid = threadIdx.x;
    int i = blockIdx.x * 1024 + tid;
    int v = (i < NKEY) ? cnt[i] : 0;
    lds[tid] = v;
    __syncthreads();
    for (int off = 1; off < 1024; off <<= 1) {
        int t = (tid >= off) ? lds[tid - off] : 0;
        __syncthreads();
        lds[tid] += t;
        __syncthreads();
    }
    if (i < NKEY) keyptr[i] = bsum[blockIdx.x] + lds[tid] - v;
}

__global__ void dinv_kernel(const int* __restrict__ keyptr, float* __restrict__ dinv, int big) {
    int i = blockIdx.x * blockDim.x + threadIdx.x;
    if (i < NN) {
        int deg;
        if (big) {
            deg = 0;
            #pragma unroll
            for (int q = 0; q < NQ; q++)
                deg += keyptr[q * NN + i + 1] - keyptr[q * NN + i];
        } else {
            deg = keyptr[(i + 1) * NSEG] - keyptr[i * NSEG];
        }
        dinv[i] = rsqrtf(1.0f + (float)deg);   // +1 self-loop
    }
}

__global__ void scatter_kernel(const void* __restrict__ eidx, const int* __restrict__ flags,
                               const int* __restrict__ keyptr, int* __restrict__ fill,
                               int* __restrict__ col, int big) {
    int e = blockIdx.x * blockDim.x + threadIdx.x;
    if (e < NE) {
        int is64 = flags[1];
        int s = edge_at(eidx, is64, (size_t)e);
        int d = edge_at(eidx, is64, (size_t)NE + e);
        int q = s & 3;
        int key = big ? (q * NN + d) : (d * 4 + q);
        int pos = keyptr[key] + atomicAdd(&fill[key], 1);
        col[pos] = s;
    }
}

// ---------------- x0 = relu(x @ W1 + b1); x0 bf16, g0 = dinv*x0 bf16 ----------------

__global__ __launch_bounds__(256) void x0_kernel(const void* __restrict__ x,
                                                 const void* __restrict__ W1,
                                                 const void* __restrict__ b1,
                                                 const int* __restrict__ flags,
                                                 const float* __restrict__ dinv,
                                                 unsigned short* __restrict__ x0b,
                                                 unsigned short* __restrict__ g0) {
    __shared__ float lw[FIN * HD];  // 32 KiB
    int isf = flags[0];
    int tid = threadIdx.x;
    for (int i = tid; i < FIN * HD; i += 256) lw[i] = fin_at(W1, isf, i);
    __syncthreads();
    int wave = tid >> 6, lane = tid & 63;
    int row0 = blockIdx.x * RPB + wave * RPW;
    if (row0 >= NN) return;
    unsigned int pa01, pa23, pb01, pb23;
    {
        unsigned short a0 = f2bf(fin_at(x, isf, (size_t)(row0 + 0) * FIN + lane));
        unsigned short a1 = f2bf(fin_at(x, isf, (size_t)(row0 + 1) * FIN + lane));
        unsigned short a2 = f2bf(fin_at(x, isf, (size_t)(row0 + 2) * FIN + lane));
        unsigned short a3 = f2bf(fin_at(x, isf, (size_t)(row0 + 3) * FIN + lane));
        unsigned short c0 = f2bf(fin_at(x, isf, (size_t)(row0 + 0) * FIN + 64 + lane));
        unsigned short c1 = f2bf(fin_at(x, isf, (size_t)(row0 + 1) * FIN + 64 + lane));
        unsigned short c2 = f2bf(fin_at(x, isf, (size_t)(row0 + 2) * FIN + 64 + lane));
        unsigned short c3 = f2bf(fin_at(x, isf, (size_t)(row0 + 3) * FIN + 64 + lane));
        pa01 = ((unsigned int)a0 << 16) | a1;  pa23 = ((unsigned int)a2 << 16) | a3;
        pb01 = ((unsigned int)c0 << 16) | c1;  pb23 = ((unsigned int)c2 << 16) | c3;
    }
    float bias = fin_at(b1, isf, lane);
    float d0 = bias, d1 = bias, d2 = bias, d3 = bias;
    #pragma unroll 8
    for (int k = 0; k < 64; k++) {
        float w = lw[k * HD + lane];
        unsigned int b01 = __shfl(pa01, k, 64);
        unsigned int b23 = __shfl(pa23, k, 64);
        union { unsigned int i; float f; } f0, f1, f2, f3;
        f0.i = b01 & 0xFFFF0000u; f1.i = b01 << 16;
        f2.i = b23 & 0xFFFF0000u; f3.i = b23 << 16;
        d0 += f0.f * w; d1 += f1.f * w; d2 += f2.f * w; d3 += f3.f * w;
    }
    #pragma unroll 8
    for (int k = 0; k < 64; k++) {
        float w = lw[(64 + k) * HD + lane];
        unsigned int b01 = __shfl(pb01, k, 64);
        unsigned int b23 = __shfl(pb23, k, 64);
        union { unsigned int i; float f; } f0, f1, f2, f3;
        f0.i = b01 & 0xFFFF0000u; f1.i = b01 << 16;
        f2.i = b23 & 0xFFFF0000u; f3.i = b23 << 16;
        d0 += f0.f * w; d1 += f1.f * w; d2 += f2.f * w; d3 += f3.f * w;
    }
    float dd[RPW] = {d0, d1, d2, d3};
    #pragma unroll
    for (int r = 0; r < RPW; r++) {
        int row = row0 + r;
        if (row >= NN) continue;
        float v = fmaxf(dd[r], 0.0f);
        x0b[(size_t)row * HD + lane] = f2bf(v);
        g0[(size_t)row * HD + lane] = f2bf(dinv[row] * v);
    }
}

// ---------------- PHASE A: XCD-partitioned partial SpMM ----------------
// Quad from the REAL hardware XCD id (s_getreg HW_REG_XCC_ID) -- R8 proved
// this gets FETCH down to compulsory-only (22 MB/layer, gathers cache-served).
// R8's cost was its scheduler (per-tile block atomic + 2 barriers = lockstep
// stalls, VALUBusy 8.8%). Here: WAVE-level chunk dispensing with ZERO
// barriers -- lane 0 atomicAdds a padded per-quad counter for 32 rows,
// broadcast by shfl; waves run independently, latency hidden by occupancy.
// Coverage insurance: wave 0 of each block sweeps all quads afterwards
// (exactly-once guaranteed by the atomics themselves).

__global__ __launch_bounds__(256, 8) void spmm_partial(const int* __restrict__ keyptr,
                                                       const int* __restrict__ colq,
                                                       const unsigned short* __restrict__ g_in,
                                                       unsigned short* __restrict__ part,
                                                       int* __restrict__ qcnt) {
    unsigned int xcc;
    asm volatile("s_getreg_b32 %0, hwreg(HW_REG_XCC_ID)" : "=s"(xcc));
    int myq = (int)(xcc & 3);
    int tid = threadIdx.x;
    int wave = tid >> 6, lane = tid & 63;
    int grp = lane >> 3, li = lane & 7;
    const char* gb = (const char*)g_in;

    auto run_quad = [&](int quad) {
        int* ctr = qcnt + quad * QPAD;
        while (true) {
            int c = 0;
            if (lane == 0) c = atomicAdd(ctr, 1);
            c = __shfl(c, 0, 64);
            if (c >= NCHQ) break;
            int rbase = c * CHROWS;
            #pragma unroll
            for (int g = 0; g < CHROWS / 8; g++) {
                int row = rbase + g * 8 + grp;
                size_t kbase = (size_t)quad * NN + row;
                int jbeg = keyptr[kbase];
                int jend = keyptr[kbase + 1];
                int cnt = jend - jbeg;

                float a0 = 0.0f, a1 = 0.0f, a2 = 0.0f, a3 = 0.0f;
                float a4 = 0.0f, a5 = 0.0f, a6 = 0.0f, a7 = 0.0f;

                for (int base = 0; base < cnt; base += 8) {
                    int idx = jbeg + base + li;
                    int cv = colq[idx < jend ? idx : (jend - 1)];
                    int rem = cnt - base;
                    #pragma unroll
                    for (int k = 0; k < 8; k++) {
                        if (k < rem) {
                            int ck = __shfl(cv, (lane & 56) + k, 64);
                            uint4 u = *reinterpret_cast<const uint4*>(
                                gb + (((size_t)ck) << 7) + (li << 4));
                            a0 += bflo(u.x); a1 += bfhi(u.x);
                            a2 += bflo(u.y); a3 += bfhi(u.y);
                            a4 += bflo(u.z); a5 += bfhi(u.z);
                            a6 += bflo(u.w); a7 += bfhi(u.w);
                        }
                    }
                }

                // fold self-loop into this row's own quad
                if (quad == (row & 3)) {
                    uint4 u = *reinterpret_cast<const uint4*>(
                        gb + (((size_t)row) << 7) + (li << 4));
                    a0 += bflo(u.x); a1 += bfhi(u.x);
                    a2 += bflo(u.y); a3 += bfhi(u.y);
                    a4 += bflo(u.z); a5 += bfhi(u.z);
                    a6 += bflo(u.w); a7 += bfhi(u.w);
                }

                u32x4 v = {pack2h(a0, a1), pack2h(a2, a3), pack2h(a4, a5), pack2h(a6, a7)};
                unsigned short* pp = part + kbase * HD + (li << 3);
                __builtin_nontemporal_store(v, reinterpret_cast<u32x4*>(pp));
            }
        }
    };

    run_quad(myq);                       // main pass: own XCD's quad
    if (wave == 0) {                     // insurance: wave 0 drains leftovers
        #pragma unroll
        for (int qi = 0; qi < NQ; qi++) run_quad((myq + qi) & 3);
    }
}

// ---------------- PHASE B: combine partials + residual mix + dense + relu ----------------

__global__ __launch_bounds__(256, 8) void layer_combine(const unsigned short* __restrict__ part,
                                                        const float* __restrict__ dinv,
                                                        const unsigned short* __restrict__ x0b,
                                                        unsigned short* __restrict__ g_out,
                                                        const void* __restrict__ convW, int layer,
                                                        const int* __restrict__ flags, float beta) {
    __shared__ float lw[HD * HD];  // 16 KiB
    int isf = flags[0];
    size_t wbase = (size_t)layer * HD * HD;
    int tid = threadIdx.x;
    for (int i = tid; i < HD * HD; i += 256) lw[i] = fin_at(convW, isf, wbase + i);
    __syncthreads();

    int wave = __builtin_amdgcn_readfirstlane(tid >> 6);
    int lane = tid & 63;
    int row0 = blockIdx.x * RPB + wave * RPW;

    float sacc[RPW];
    float dsc[RPW];
    #pragma unroll
    for (int r = 0; r < RPW; r++) {
        int row = row0 + r;
        if (row >= NN) { sacc[r] = 0.0f; dsc[r] = 1.0f; continue; }
        float a = 0.0f;
        #pragma unroll
        for (int q = 0; q < NQ; q++) {
            unsigned short u = __builtin_nontemporal_load(
                part + ((size_t)q * NN + row) * HD + lane);
            a += h2f(u);
        }
        float di = dinv[row];
        dsc[r] = di;
        sacc[r] = 0.9f * (di * a) + 0.1f * bf2f(x0b[((size_t)row << 6) + lane]);
    }

    unsigned int p01 = ((unsigned int)f2bf(sacc[0]) << 16) | f2bf(sacc[1]);
    unsigned int p23 = ((unsigned int)f2bf(sacc[2]) << 16) | f2bf(sacc[3]);
    float d0 = 0.0f, d1 = 0.0f, d2 = 0.0f, d3 = 0.0f;
    #pragma unroll 8
    for (int k = 0; k < 64; k++) {
        float w = lw[k * HD + lane];
        unsigned int b01 = __shfl(p01, k, 64);
        unsigned int b23 = __shfl(p23, k, 64);
        union { unsigned int i; float f; } f0, f1, f2, f3;
        f0.i = b01 & 0xFFFF0000u; f1.i = b01 << 16;
        f2.i = b23 & 0xFFFF0000u; f3.i = b23 << 16;
        d0 += f0.f * w; d1 += f1.f * w;
        d2 += f2.f * w; d3 += f3.f * w;
    }

    float dd[RPW] = {d0, d1, d2, d3};
    float omb = 1.0f - beta;
    #pragma unroll
    for (int r = 0; r < RPW; r++) {
        int row = row0 + r;
        if (row >= NN) continue;
        float res = omb * sacc[r] + beta * dd[r];
        g_out[((size_t)row << 6) + lane] = f2bf(dsc[r] * fmaxf(res, 0.0f));
    }
}

// ---------------- FALLBACK: round-3 fused layer (dst-major CSR, NSEG=4) ----------------

__global__ __launch_bounds__(256, 8) void layer_fused(const int* __restrict__ keyptr,
                                                      const int* __restrict__ col,
                                                      const float* __restrict__ dinv,
                                                      const unsigned short* __restrict__ g_in,
                                                      const unsigned short* __restrict__ x0b,
                                                      unsigned short* __restrict__ g_out,
                                                      const void* __restrict__ convW, int layer,
                                                      const int* __restrict__ flags, float beta) {
    __shared__ float lw[HD * HD];  // 16 KiB
    int isf = flags[0];
    size_t wbase = (size_t)layer * HD * HD;
    int tid = threadIdx.x;
    for (int i = tid; i < HD * HD; i += 256) lw[i] = fin_at(convW, isf, wbase + i);
    __syncthreads();

    int wave = __builtin_amdgcn_readfirstlane(tid >> 6);
    int lane = tid & 63;
    int eslot = lane >> 3;
    int sbyte = (lane & 7) << 4;
    const char* gb = (const char*)g_in;

    int row0 = blockIdx.x * RPB + wave * RPW;

    float sacc[RPW];
    float dsc[RPW];
    #pragma unroll
    for (int r = 0; r < RPW; r++) {
        int row = row0 + r;
        if (row >= NN) { sacc[r] = 0.0f; dsc[r] = 1.0f; continue; }
        int start = keyptr[row * NSEG];
        int end   = keyptr[(row + 1) * NSEG];

        float a0 = 0.0f, a1 = 0.0f, a2 = 0.0f, a3 = 0.0f;
        float a4 = 0.0f, a5 = 0.0f, a6 = 0.0f, a7 = 0.0f;

        for (int j = start; j < end; j += 32) {
            int le = end - 1;
            int i0 = j + eslot, i1 = i0 + 8, i2 = i0 + 16, i3 = i0 + 24;
            int c0 = col[i0 < end ? i0 : le];
            int c1 = col[i1 < end ? i1 : le];
            int c2 = col[i2 < end ? i2 : le];
            int c3 = col[i3 < end ? i3 : le];
            uint4 u0 = *reinterpret_cast<const uint4*>(gb + (((size_t)c0) << 7) + sbyte);
            uint4 u1 = *reinterpret_cast<const uint4*>(gb + (((size_t)c1) << 7) + sbyte);
            uint4 u2 = *reinterpret_cast<const uint4*>(gb + (((size_t)c2) << 7) + sbyte);
            uint4 u3 = *reinterpret_cast<const uint4*>(gb + (((size_t)c3) << 7) + sbyte);
            float m0 = (i0 < end) ? 1.0f : 0.0f;
            float m1 = (i1 < end) ? 1.0f : 0.0f;
            float m2 = (i2 < end) ? 1.0f : 0.0f;
            float m3 = (i3 < end) ? 1.0f : 0.0f;
            a0 = fmaf(m0, bflo(u0.x), a0); a1 = fmaf(m0, bfhi(u0.x), a1);
            a2 = fmaf(m0, bflo(u0.y), a2); a3 = fmaf(m0, bfhi(u0.y), a3);
            a4 = fmaf(m0, bflo(u0.z), a4); a5 = fmaf(m0, bfhi(u0.z), a5);
            a6 = fmaf(m0, bflo(u0.w), a6); a7 = fmaf(m0, bfhi(u0.w), a7);
            a0 = fmaf(m1, bflo(u1.x), a0); a1 = fmaf(m1, bfhi(u1.x), a1);
            a2 = fmaf(m1, bflo(u1.y), a2); a3 = fmaf(m1, bfhi(u1.y), a3);
            a4 = fmaf(m1, bflo(u1.z), a4); a5 = fmaf(m1, bfhi(u1.z), a5);
            a6 = fmaf(m1, bflo(u1.w), a6); a7 = fmaf(m1, bfhi(u1.w), a7);
            a0 = fmaf(m2, bflo(u2.x), a0); a1 = fmaf(m2, bfhi(u2.x), a1);
            a2 = fmaf(m2, bflo(u2.y), a2); a3 = fmaf(m2, bfhi(u2.y), a3);
            a4 = fmaf(m2, bflo(u2.z), a4); a5 = fmaf(m2, bfhi(u2.z), a5);
            a6 = fmaf(m2, bflo(u2.w), a6); a7 = fmaf(m2, bfhi(u2.w), a7);
            a0 = fmaf(m3, bflo(u3.x), a0); a1 = fmaf(m3, bfhi(u3.x), a1);
            a2 = fmaf(m3, bflo(u3.y), a2); a3 = fmaf(m3, bfhi(u3.y), a3);
            a4 = fmaf(m3, bflo(u3.z), a4); a5 = fmaf(m3, bfhi(u3.z), a5);
            a6 = fmaf(m3, bflo(u3.w), a6); a7 = fmaf(m3, bfhi(u3.w), a7);
        }

        a0 += __shfl_xor(a0, 8, 64); a0 += __shfl_xor(a0, 16, 64); a0 += __shfl_xor(a0, 32, 64);
        a1 += __shfl_xor(a1, 8, 64); a1 += __shfl_xor(a1, 16, 64); a1 += __shfl_xor(a1, 32, 64);
        a2 += __shfl_xor(a2, 8, 64); a2 += __shfl_xor(a2, 16, 64); a2 += __shfl_xor(a2, 32, 64);
        a3 += __shfl_xor(a3, 8, 64); a3 += __shfl_xor(a3, 16, 64); a3 += __shfl_xor(a3, 32, 64);
        a4 += __shfl_xor(a4, 8, 64); a4 += __shfl_xor(a4, 16, 64); a4 += __shfl_xor(a4, 32, 64);
        a5 += __shfl_xor(a5, 8, 64); a5 += __shfl_xor(a5, 16, 64); a5 += __shfl_xor(a5, 32, 64);
        a6 += __shfl_xor(a6, 8, 64); a6 += __shfl_xor(a6, 16, 64); a6 += __shfl_xor(a6, 32, 64);
        a7 += __shfl_xor(a7, 8, 64); a7 += __shfl_xor(a7, 16, 64); a7 += __shfl_xor(a7, 32, 64);

        int srcl = lane >> 3;
        float t0 = __shfl(a0, srcl, 64);
        float t1 = __shfl(a1, srcl, 64);
        float t2 = __shfl(a2, srcl, 64);
        float t3 = __shfl(a3, srcl, 64);
        float t4 = __shfl(a4, srcl, 64);
        float t5 = __shfl(a5, srcl, 64);
        float t6 = __shfl(a6, srcl, 64);
        float t7 = __shfl(a7, srcl, 64);
        int b0 = lane & 1, b1 = (lane >> 1) & 1, b2 = (lane >> 2) & 1;
        float s01 = b0 ? t1 : t0, s23 = b0 ? t3 : t2;
        float s45 = b0 ? t5 : t4, s67 = b0 ? t7 : t6;
        float sA = b1 ? s23 : s01, sB = b1 ? s67 : s45;
        float gsum = b2 ? sB : sA;

        float a = gsum + bf2f(g_in[((size_t)row << 6) + lane]);
        float di = dinv[row];
        dsc[r] = di;
        sacc[r] = 0.9f * (di * a) + 0.1f * bf2f(x0b[((size_t)row << 6) + lane]);
    }

    unsigned int p01 = ((unsigned int)f2bf(sacc[0]) << 16) | f2bf(sacc[1]);
    unsigned int p23 = ((unsigned int)f2bf(sacc[2]) << 16) | f2bf(sacc[3]);
    float d0 = 0.0f, d1 = 0.0f, d2 = 0.0f, d3 = 0.0f;
    #pragma unroll 8
    for (int k = 0; k < 64; k++) {
        float w = lw[k * HD + lane];
        unsigned int b01 = __shfl(p01, k, 64);
        unsigned int b23 = __shfl(p23, k, 64);
        union { unsigned int i; float f; } f0, f1, f2, f3;
        f0.i = b01 & 0xFFFF0000u; f1.i = b01 << 16;
        f2.i = b23 & 0xFFFF0000u; f3.i = b23 << 16;
        d0 += f0.f * w; d1 += f1.f * w;
        d2 += f2.f * w; d3 += f3.f * w;
    }

    float dd[RPW] = {d0, d1, d2, d3};
    float omb = 1.0f - beta;
    #pragma unroll
    for (int r = 0; r < RPW; r++) {
        int row = row0 + r;
        if (row >= NN) continue;
        float res = omb * sacc[r] + beta * dd[r];
        g_out[((size_t)row << 6) + lane] = f2bf(dsc[r] * fmaxf(res, 0.0f));
    }
}

// ---------------- out = log_softmax(h @ W2 + b2), h = g/dinv ----------------

__global__ __launch_bounds__(256) void out_kernel(const unsigned short* __restrict__ g,
                                                  const float* __restrict__ dinv,
                                                  const void* __restrict__ W2,
                                                  const void* __restrict__ b2,
                                                  const int* __restrict__ flags,
                                                  void* __restrict__ out) {
    __shared__ float lw[HD * 64];
    int isf = flags[0];
    int tid = threadIdx.x;
    for (int i = tid; i < HD * 64; i += 256) {
        int k = i >> 6, j = i & 63;
        lw[i] = (j < NC) ? fin_at(W2, isf, (size_t)k * NC + j) : 0.0f;
    }
    __syncthreads();
    int row = blockIdx.x * 4 + (tid >> 6);
    int lane = tid & 63;
    if (row >= NN) return;
    float hv = bf2f(g[(size_t)row * HD + lane]) / dinv[row];
    float acc = (lane < NC) ? fin_at(b2, isf, lane) : 0.0f;
    #pragma unroll 8
    for (int k = 0; k < 64; k++) {
        float hk = __shfl(hv, k, 64);
        acc += hk * lw[k * 64 + lane];
    }
    float mv = (lane < NC) ? acc : -1e30f;
    for (int off = 32; off > 0; off >>= 1) mv = fmaxf(mv, __shfl_xor(mv, off, 64));
    float ex = (lane < NC) ? expf(acc - mv) : 0.0f;
    float se = ex;
    for (int off = 32; off > 0; off >>= 1) se += __shfl_xor(se, off, 64);
    float res = acc - mv - logf(se);
    if (lane < NC) {
        size_t oi = (size_t)row * NC + lane;
        if (isf) ((float*)out)[oi] = res;
        else     ((__hip_bfloat16*)out)[oi] = __float2bfloat16(res);
    }
}

// ---------------- host ----------------

static inline size_t align256(size_t x) { return (x + 255) & ~(size_t)255; }

extern "C" void kernel_launch(void* const* d_in, const int* in_sizes, int n_in,
                              void* d_out, int out_size, void* d_ws, size_t ws_size,
                              hipStream_t stream) {
    const void* x     = d_in[0];
    const void* eidx  = d_in[1];
    const void* W1    = d_in[2];
    const void* b1    = d_in[3];
    const void* convW = d_in[4];
    const void* W2    = d_in[5];
    const void* b2    = d_in[6];

    char* p = (char*)d_ws;
    size_t off = 0;
    auto alloc = [&](size_t bytes) { void* r = p + off; off += align256(bytes); return r; };
    int*            flags   = (int*)alloc(256);
    int*            cnt     = (int*)alloc((size_t)NKEY * 4);
    int*            fill    = (int*)alloc((size_t)NKEY * 4);
    int*            keyptr  = (int*)alloc((size_t)(NKEY + 1) * 4);
    int*            bsum    = (int*)alloc((size_t)KB * 4);
    float*          dinv    = (float*)alloc((size_t)NN * 4);
    int*            col     = (int*)alloc((size_t)NE * 4);
    unsigned short* x0b     = (unsigned short*)alloc((size_t)NN * HD * 2);
    unsigned short* hA      = (unsigned short*)alloc((size_t)NN * HD * 2);
    unsigned short* hB      = (unsigned short*)alloc((size_t)NN * HD * 2);
    int*            qcnt    = (int*)alloc((size_t)NL * NQ * QPAD * 4);  // padded per-layer counters

    size_t part_bytes = (size_t)NQ * NN * HD * 2;   // 51.2 MB fp16 partials
    int big = (off + part_bytes) <= ws_size;
    unsigned short* part = (unsigned short*)(p + off);   // only used if big

    detect_kernel<<<1, 64, 0, stream>>>(x, eidx, flags);

    hipMemsetAsync(cnt, 0, (size_t)NKEY * 4, stream);
    hipMemsetAsync(fill, 0, (size_t)NKEY * 4, stream);
    hipMemsetAsync(qcnt, 0, (size_t)NL * NQ * QPAD * 4, stream);
    key_count<<<(NE + 255) / 256, 256, 0, stream>>>(eidx, flags, cnt, big);
    scan_reduce<<<KB, 1024, 0, stream>>>(cnt, bsum);
    scan_mid<<<1, 1024, 0, stream>>>(bsum, keyptr + NKEY);
    scan_final<<<KB, 1024, 0, stream>>>(cnt, bsum, keyptr);
    dinv_kernel<<<(NN + 255) / 256, 256, 0, stream>>>(keyptr, dinv, big);
    scatter_kernel<<<(NE + 255) / 256, 256, 0, stream>>>(eidx, flags, keyptr, fill, col, big);

    int fb = (NN + RPB - 1) / RPB;  // 6250 blocks
    x0_kernel<<<fb, 256, 0, stream>>>(x, W1, b1, flags, dinv, x0b, hA);

    unsigned short* gin = hA;
    unsigned short* gout = hB;
    for (int l = 0; l < NL; l++) {
        float beta = logf(0.5f / (float)(l + 1) + 1.0f);
        if (big) {
            spmm_partial<<<PGRID, 256, 0, stream>>>(keyptr, col, gin, part,
                                                    qcnt + (size_t)l * NQ * QPAD);
            layer_combine<<<fb, 256, 0, stream>>>(part, dinv, x0b, gout,
                                                  convW, l, flags, beta);
        } else {
            layer_fused<<<fb, 256, 0, stream>>>(keyptr, col, dinv, gin, x0b, gout,
                                                convW, l, flags, beta);
        }
        unsigned short* t = gin; gin = gout; gout = t;
    }
    out_kernel<<<(NN + 3) / 4, 256, 0, stream>>>(gin, dinv, W2, b2, flags, (void*)d_out);
}

// Round 10
// 6615.894 us; speedup vs baseline: 3.0262x; 1.6967x over previous
//
#include <hip/hip_runtime.h>
#include <hip/hip_bf16.h>
#include <math.h>

#define NN 100000
#define NE 3200000
#define FIN 128
#define HD 64
#define NL 64
#define NC 47
#define RPW 4               // rows per wave
#define WPB 4               // waves per block
#define RPB (RPW * WPB)     // rows per block = 16

#define SEGSH 13            // source segment = 8192 nodes (kept for CSR build)
#define NSEG 13             // ceil(100000 / 8192)
#define NKEY (NN * NSEG)    // 1.3M (dst, seg) keys
#define KB ((NKEY + 1023) / 1024)   // scan blocks

// ---------------- helpers ----------------

__device__ __forceinline__ float bf2f(unsigned short u) {
    union { unsigned int i; float f; } v; v.i = ((unsigned int)u) << 16; return v.f;
}
__device__ __forceinline__ unsigned short f2bf(float f) {
    __hip_bfloat16 h = __float2bfloat16(f);   // RNE
    return *reinterpret_cast<unsigned short*>(&h);
}
__device__ __forceinline__ float bflo(unsigned int u) {
    union { unsigned int i; float f; } v; v.i = u << 16; return v.f;
}
__device__ __forceinline__ float bfhi(unsigned int u) {
    union { unsigned int i; float f; } v; v.i = u & 0xFFFF0000u; return v.f;
}
__device__ __forceinline__ float fin_at(const void* p, int isf32, size_t i) {
    return isf32 ? ((const float*)p)[i]
                 : __bfloat162float(((const __hip_bfloat16*)p)[i]);
}
__device__ __forceinline__ int edge_at(const void* p, int is64, size_t i) {
    return is64 ? (int)((const long long*)p)[i] : ((const int*)p)[i];
}

// ---------------- runtime dtype detection ----------------
// flags[0]: 1 = float inputs are fp32, 0 = bf16
// flags[1]: 1 = edge_index is int64, 0 = int32

__global__ void detect_kernel(const void* __restrict__ x, const void* __restrict__ eidx,
                              int* __restrict__ flags) {
    if (threadIdx.x == 0 && blockIdx.x == 0) {
        const unsigned short* u = (const unsigned short*)x;
        int sane = 0;
        for (int i = 0; i < 64; i++) {
            unsigned short v = u[2 * i];
            int e = (v >> 7) & 0xFF;
            if ((v & 0x7FFF) == 0 || (e >= 90 && e <= 141)) sane++;
        }
        flags[0] = (sane >= 48) ? 0 : 1;
        const int* e32 = (const int*)eidx;
        int nz = 0;
        for (int i = 0; i < 64; i++) if (e32[2 * i + 1] != 0) nz++;
        flags[1] = (nz == 0) ? 1 : 0;
    }
}

// ---------------- segmented-CSR build (key = dst*NSEG + seg) ----

__global__ void key_count(const void* __restrict__ eidx, const int* __restrict__ flags,
                          int* __restrict__ cnt) {
    int e = blockIdx.x * blockDim.x + threadIdx.x;
    if (e < NE) {
        int is64 = flags[1];
        int s = edge_at(eidx, is64, (size_t)e);
        int d = edge_at(eidx, is64, (size_t)NE + e);
        atomicAdd(&cnt[d * NSEG + (s >> SEGSH)], 1);
    }
}

__global__ __launch_bounds__(1024) void scan_reduce(const int* __restrict__ cnt,
                                                    int* __restrict__ bsum) {
    __shared__ int lds[1024];
    int tid = threadIdx.x;
    int i = blockIdx.x * 1024 + tid;
    lds[tid] = (i < NKEY) ? cnt[i] : 0;
    __syncthreads();
    for (int off = 512; off > 0; off >>= 1) {
        if (tid < off) lds[tid] += lds[tid + off];
        __syncthreads();
    }
    if (tid == 0) bsum[blockIdx.x] = lds[0];
}

__global__ __launch_bounds__(1024) void scan_mid(int* __restrict__ bsum, int* __restrict__ total_out) {
    __shared__ int lds[1024];
    __shared__ int base_s;
    int tid = threadIdx.x;
    if (tid == 0) base_s = 0;
    __syncthreads();
    for (int chunk = 0; chunk < KB; chunk += 1024) {
        int i = chunk + tid;
        int v = (i < KB) ? bsum[i] : 0;
        lds[tid] = v;
        __syncthreads();
        for (int off = 1; off < 1024; off <<= 1) {
            int t = (tid >= off) ? lds[tid - off] : 0;
            __syncthreads();
            lds[tid] += t;
            __syncthreads();
        }
        int incl = lds[tid];
        int base = base_s;
        if (i < KB) bsum[i] = base + incl - v;
        __syncthreads();
        if (tid == 1023) base_s = base + incl;
        __syncthreads();
    }
    if (tid == 0) *total_out = base_s;   // == NE
}

__global__ __launch_bounds__(1024) void scan_final(const int* __restrict__ cnt,
                                                   const int* __restrict__ bsum,
                                                   int* __restrict__ keyptr) {
    __shared__ int lds[1024];
    int tid = threadIdx.x;
    int i = blockIdx.x * 1024 + tid;
    int v = (i < NKEY) ? cnt[i] : 0;
    lds[tid] = v;
    __syncthreads();
    for (int off = 1; off < 1024; off <<= 1) {
        int t = (tid >= off) ? lds[tid - off] : 0;
        __syncthreads();
        lds[tid] += t;
        __syncthreads();
    }
    if (i < NKEY) keyptr[i] = bsum[blockIdx.x] + lds[tid] - v;
}

__global__ void dinv_kernel(const int* __restrict__ keyptr, float* __restrict__ dinv) {
    int i = blockIdx.x * blockDim.x + threadIdx.x;
    if (i < NN) {
        int deg = keyptr[(i + 1) * NSEG] - keyptr[i * NSEG];
        dinv[i] = rsqrtf(1.0f + (float)deg);   // +1 self-loop
    }
}

__global__ void scatter_kernel(const void* __restrict__ eidx, const int* __restrict__ flags,
                               const int* __restrict__ keyptr, int* __restrict__ fill,
                               int* __restrict__ col) {
    int e = blockIdx.x * blockDim.x + threadIdx.x;
    if (e < NE) {
        int is64 = flags[1];
        int s = edge_at(eidx, is64, (size_t)e);
        int d = edge_at(eidx, is64, (size_t)NE + e);
        int key = d * NSEG + (s >> SEGSH);
        int pos = keyptr[key] + atomicAdd(&fill[key], 1);
        col[pos] = s;
    }
}

// ---------------- x0 = relu(x @ W1 + b1); x0 bf16, g0 = dinv*x0 bf16 ----------------

__global__ __launch_bounds__(256) void x0_kernel(const void* __restrict__ x,
                                                 const void* __restrict__ W1,
                                                 const void* __restrict__ b1,
                                                 const int* __restrict__ flags,
                                                 const float* __restrict__ dinv,
                                                 unsigned short* __restrict__ x0b,
                                                 unsigned short* __restrict__ g0) {
    __shared__ float lw[FIN * HD];  // 32 KiB
    int isf = flags[0];
    int tid = threadIdx.x;
    for (int i = tid; i < FIN * HD; i += 256) lw[i] = fin_at(W1, isf, i);
    __syncthreads();
    int wave = tid >> 6, lane = tid & 63;
    int row0 = blockIdx.x * RPB + wave * RPW;
    if (row0 >= NN) return;
    unsigned int pa01, pa23, pb01, pb23;
    {
        unsigned short a0 = f2bf(fin_at(x, isf, (size_t)(row0 + 0) * FIN + lane));
        unsigned short a1 = f2bf(fin_at(x, isf, (size_t)(row0 + 1) * FIN + lane));
        unsigned short a2 = f2bf(fin_at(x, isf, (size_t)(row0 + 2) * FIN + lane));
        unsigned short a3 = f2bf(fin_at(x, isf, (size_t)(row0 + 3) * FIN + lane));
        unsigned short c0 = f2bf(fin_at(x, isf, (size_t)(row0 + 0) * FIN + 64 + lane));
        unsigned short c1 = f2bf(fin_at(x, isf, (size_t)(row0 + 1) * FIN + 64 + lane));
        unsigned short c2 = f2bf(fin_at(x, isf, (size_t)(row0 + 2) * FIN + 64 + lane));
        unsigned short c3 = f2bf(fin_at(x, isf, (size_t)(row0 + 3) * FIN + 64 + lane));
        pa01 = ((unsigned int)a0 << 16) | a1;  pa23 = ((unsigned int)a2 << 16) | a3;
        pb01 = ((unsigned int)c0 << 16) | c1;  pb23 = ((unsigned int)c2 << 16) | c3;
    }
    float bias = fin_at(b1, isf, lane);
    float d0 = bias, d1 = bias, d2 = bias, d3 = bias;
    #pragma unroll 8
    for (int k = 0; k < 64; k++) {
        float w = lw[k * HD + lane];
        unsigned int b01 = __shfl(pa01, k, 64);
        unsigned int b23 = __shfl(pa23, k, 64);
        union { unsigned int i; float f; } f0, f1, f2, f3;
        f0.i = b01 & 0xFFFF0000u; f1.i = b01 << 16;
        f2.i = b23 & 0xFFFF0000u; f3.i = b23 << 16;
        d0 += f0.f * w; d1 += f1.f * w; d2 += f2.f * w; d3 += f3.f * w;
    }
    #pragma unroll 8
    for (int k = 0; k < 64; k++) {
        float w = lw[(64 + k) * HD + lane];
        unsigned int b01 = __shfl(pb01, k, 64);
        unsigned int b23 = __shfl(pb23, k, 64);
        union { unsigned int i; float f; } f0, f1, f2, f3;
        f0.i = b01 & 0xFFFF0000u; f1.i = b01 << 16;
        f2.i = b23 & 0xFFFF0000u; f3.i = b23 << 16;
        d0 += f0.f * w; d1 += f1.f * w; d2 += f2.f * w; d3 += f3.f * w;
    }
    float dd[RPW] = {d0, d1, d2, d3};
    #pragma unroll
    for (int r = 0; r < RPW; r++) {
        int row = row0 + r;
        if (row >= NN) continue;
        float v = fmaxf(dd[r], 0.0f);
        x0b[(size_t)row * HD + lane] = f2bf(v);
        g0[(size_t)row * HD + lane] = f2bf(dinv[row] * v);
    }
}

// ---------------- fused layer ----------------
// Wide-MLP gather: 8 lanes per edge row x dwordx4 (16 B/lane) -> ONE vector
// load fetches 8 full 128-B edge rows; 4 such loads per chunk = 32 edges in
// flight per wave. Edge indices via per-lane vector load col[j + 8g + (lane>>3)]
// (coalesced). Tails branchless: index clamp + fmaf mask.
// Accumulators slice-packed (8 cols/lane); folded to lane=col once per row.
// p[d] = dinv[d]*(sum g[s] + g[d]); s = .9p + .1x0; h = relu((1-b)s + b s@Wl);
// g_out = dinv*h.

__global__ __launch_bounds__(256, 8) void layer_fused(const int* __restrict__ keyptr,
                                                      const int* __restrict__ col,
                                                      const float* __restrict__ dinv,
                                                      const unsigned short* __restrict__ g_in,
                                                      const unsigned short* __restrict__ x0b,
                                                      unsigned short* __restrict__ g_out,
                                                      const void* __restrict__ convW, int layer,
                                                      const int* __restrict__ flags, float beta) {
    __shared__ float lw[HD * HD];  // 16 KiB
    int isf = flags[0];
    size_t wbase = (size_t)layer * HD * HD;
    int tid = threadIdx.x;
    for (int i = tid; i < HD * HD; i += 256) lw[i] = fin_at(convW, isf, wbase + i);
    __syncthreads();

    // force wave-uniform SGPR value so keyptr loads become scalar loads
    int wave = __builtin_amdgcn_readfirstlane(tid >> 6);
    int lane = tid & 63;
    int eslot = lane >> 3;            // edge slot 0..7 within a group
    int sbyte = (lane & 7) << 4;      // byte offset of this lane's 16-B slice
    const char* gb = (const char*)g_in;

    int row0 = blockIdx.x * RPB + wave * RPW;

    float sacc[RPW];
    float dsc[RPW];
    #pragma unroll
    for (int r = 0; r < RPW; r++) {
        int row = row0 + r;
        if (row >= NN) { sacc[r] = 0.0f; dsc[r] = 1.0f; continue; }
        int start = keyptr[row * NSEG];
        int end   = keyptr[(row + 1) * NSEG];

        float a0 = 0.0f, a1 = 0.0f, a2 = 0.0f, a3 = 0.0f;
        float a4 = 0.0f, a5 = 0.0f, a6 = 0.0f, a7 = 0.0f;

        for (int j = start; j < end; j += 32) {
            int le = end - 1;
            int i0 = j + eslot, i1 = i0 + 8, i2 = i0 + 16, i3 = i0 + 24;
            int c0 = col[i0 < end ? i0 : le];
            int c1 = col[i1 < end ? i1 : le];
            int c2 = col[i2 < end ? i2 : le];
            int c3 = col[i3 < end ? i3 : le];
            uint4 u0 = *reinterpret_cast<const uint4*>(gb + (((size_t)c0) << 7) + sbyte);
            uint4 u1 = *reinterpret_cast<const uint4*>(gb + (((size_t)c1) << 7) + sbyte);
            uint4 u2 = *reinterpret_cast<const uint4*>(gb + (((size_t)c2) << 7) + sbyte);
            uint4 u3 = *reinterpret_cast<const uint4*>(gb + (((size_t)c3) << 7) + sbyte);
            float m0 = (i0 < end) ? 1.0f : 0.0f;
            float m1 = (i1 < end) ? 1.0f : 0.0f;
            float m2 = (i2 < end) ? 1.0f : 0.0f;
            float m3 = (i3 < end) ? 1.0f : 0.0f;
            a0 = fmaf(m0, bflo(u0.x), a0); a1 = fmaf(m0, bfhi(u0.x), a1);
            a2 = fmaf(m0, bflo(u0.y), a2); a3 = fmaf(m0, bfhi(u0.y), a3);
            a4 = fmaf(m0, bflo(u0.z), a4); a5 = fmaf(m0, bfhi(u0.z), a5);
            a6 = fmaf(m0, bflo(u0.w), a6); a7 = fmaf(m0, bfhi(u0.w), a7);
            a0 = fmaf(m1, bflo(u1.x), a0); a1 = fmaf(m1, bfhi(u1.x), a1);
            a2 = fmaf(m1, bflo(u1.y), a2); a3 = fmaf(m1, bfhi(u1.y), a3);
            a4 = fmaf(m1, bflo(u1.z), a4); a5 = fmaf(m1, bfhi(u1.z), a5);
            a6 = fmaf(m1, bflo(u1.w), a6); a7 = fmaf(m1, bfhi(u1.w), a7);
            a0 = fmaf(m2, bflo(u2.x), a0); a1 = fmaf(m2, bfhi(u2.x), a1);
            a2 = fmaf(m2, bflo(u2.y), a2); a3 = fmaf(m2, bfhi(u2.y), a3);
            a4 = fmaf(m2, bflo(u2.z), a4); a5 = fmaf(m2, bfhi(u2.z), a5);
            a6 = fmaf(m2, bflo(u2.w), a6); a7 = fmaf(m2, bfhi(u2.w), a7);
            a0 = fmaf(m3, bflo(u3.x), a0); a1 = fmaf(m3, bfhi(u3.x), a1);
            a2 = fmaf(m3, bflo(u3.y), a2); a3 = fmaf(m3, bfhi(u3.y), a3);
            a4 = fmaf(m3, bflo(u3.z), a4); a5 = fmaf(m3, bfhi(u3.z), a5);
            a6 = fmaf(m3, bflo(u3.w), a6); a7 = fmaf(m3, bfhi(u3.w), a7);
        }

        // reduce across the 8 edge-slot classes (lanes differing in bits 3..5)
        a0 += __shfl_xor(a0, 8, 64); a0 += __shfl_xor(a0, 16, 64); a0 += __shfl_xor(a0, 32, 64);
        a1 += __shfl_xor(a1, 8, 64); a1 += __shfl_xor(a1, 16, 64); a1 += __shfl_xor(a1, 32, 64);
        a2 += __shfl_xor(a2, 8, 64); a2 += __shfl_xor(a2, 16, 64); a2 += __shfl_xor(a2, 32, 64);
        a3 += __shfl_xor(a3, 8, 64); a3 += __shfl_xor(a3, 16, 64); a3 += __shfl_xor(a3, 32, 64);
        a4 += __shfl_xor(a4, 8, 64); a4 += __shfl_xor(a4, 16, 64); a4 += __shfl_xor(a4, 32, 64);
        a5 += __shfl_xor(a5, 8, 64); a5 += __shfl_xor(a5, 16, 64); a5 += __shfl_xor(a5, 32, 64);
        a6 += __shfl_xor(a6, 8, 64); a6 += __shfl_xor(a6, 16, 64); a6 += __shfl_xor(a6, 32, 64);
        a7 += __shfl_xor(a7, 8, 64); a7 += __shfl_xor(a7, 16, 64); a7 += __shfl_xor(a7, 32, 64);

        // redistribute: lane c takes acc[c&7] from lane (c>>3)
        int srcl = lane >> 3;
        float t0 = __shfl(a0, srcl, 64);
        float t1 = __shfl(a1, srcl, 64);
        float t2 = __shfl(a2, srcl, 64);
        float t3 = __shfl(a3, srcl, 64);
        float t4 = __shfl(a4, srcl, 64);
        float t5 = __shfl(a5, srcl, 64);
        float t6 = __shfl(a6, srcl, 64);
        float t7 = __shfl(a7, srcl, 64);
        int b0 = lane & 1, b1 = (lane >> 1) & 1, b2 = (lane >> 2) & 1;
        float s01 = b0 ? t1 : t0, s23 = b0 ? t3 : t2;
        float s45 = b0 ? t5 : t4, s67 = b0 ? t7 : t6;
        float sA = b1 ? s23 : s01, sB = b1 ? s67 : s45;
        float gsum = b2 ? sB : sA;

        float a = gsum + bf2f(g_in[((size_t)row << 6) + lane]);  // + self-loop
        float di = dinv[row];
        dsc[r] = di;
        sacc[r] = 0.9f * (di * a) + 0.1f * bf2f(x0b[((size_t)row << 6) + lane]);
    }

    // dense: d = s @ Wl ; s packed 2-rows-per-dword bf16, broadcast via shfl
    unsigned int p01 = ((unsigned int)f2bf(sacc[0]) << 16) | f2bf(sacc[1]);
    unsigned int p23 = ((unsigned int)f2bf(sacc[2]) << 16) | f2bf(sacc[3]);
    float d0 = 0.0f, d1 = 0.0f, d2 = 0.0f, d3 = 0.0f;
    #pragma unroll 8
    for (int k = 0; k < 64; k++) {
        float w = lw[k * HD + lane];
        unsigned int b01 = __shfl(p01, k, 64);
        unsigned int b23 = __shfl(p23, k, 64);
        union { unsigned int i; float f; } f0, f1, f2, f3;
        f0.i = b01 & 0xFFFF0000u; f1.i = b01 << 16;
        f2.i = b23 & 0xFFFF0000u; f3.i = b23 << 16;
        d0 += f0.f * w; d1 += f1.f * w;
        d2 += f2.f * w; d3 += f3.f * w;
    }

    float dd[RPW] = {d0, d1, d2, d3};
    float omb = 1.0f - beta;
    #pragma unroll
    for (int r = 0; r < RPW; r++) {
        int row = row0 + r;
        if (row >= NN) continue;
        float res = omb * sacc[r] + beta * dd[r];
        g_out[((size_t)row << 6) + lane] = f2bf(dsc[r] * fmaxf(res, 0.0f));
    }
}

// ---------------- out = log_softmax(h @ W2 + b2), h = g/dinv ----------------

__global__ __launch_bounds__(256) void out_kernel(const unsigned short* __restrict__ g,
                                                  const float* __restrict__ dinv,
                                                  const void* __restrict__ W2,
                                                  const void* __restrict__ b2,
                                                  const int* __restrict__ flags,
                                                  void* __restrict__ out) {
    __shared__ float lw[HD * 64];
    int isf = flags[0];
    int tid = threadIdx.x;
    for (int i = tid; i < HD * 64; i += 256) {
        int k = i >> 6, j = i & 63;
        lw[i] = (j < NC) ? fin_at(W2, isf, (size_t)k * NC + j) : 0.0f;
    }
    __syncthreads();
    int row = blockIdx.x * 4 + (tid >> 6);
    int lane = tid & 63;
    if (row >= NN) return;
    float hv = bf2f(g[(size_t)row * HD + lane]) / dinv[row];
    float acc = (lane < NC) ? fin_at(b2, isf, lane) : 0.0f;
    #pragma unroll 8
    for (int k = 0; k < 64; k++) {
        float hk = __shfl(hv, k, 64);
        acc += hk * lw[k * 64 + lane];
    }
    float mv = (lane < NC) ? acc : -1e30f;
    for (int off = 32; off > 0; off >>= 1) mv = fmaxf(mv, __shfl_xor(mv, off, 64));
    float ex = (lane < NC) ? expf(acc - mv) : 0.0f;
    float se = ex;
    for (int off = 32; off > 0; off >>= 1) se += __shfl_xor(se, off, 64);
    float res = acc - mv - logf(se);
    if (lane < NC) {
        size_t oi = (size_t)row * NC + lane;
        if (isf) ((float*)out)[oi] = res;
        else     ((__hip_bfloat16*)out)[oi] = __float2bfloat16(res);
    }
}

// ---------------- host ----------------

static inline size_t align256(size_t x) { return (x + 255) & ~(size_t)255; }

extern "C" void kernel_launch(void* const* d_in, const int* in_sizes, int n_in,
                              void* d_out, int out_size, void* d_ws, size_t ws_size,
                              hipStream_t stream) {
    const void* x     = d_in[0];
    const void* eidx  = d_in[1];
    const void* W1    = d_in[2];
    const void* b1    = d_in[3];
    const void* convW = d_in[4];
    const void* W2    = d_in[5];
    const void* b2    = d_in[6];

    char* p = (char*)d_ws;
    size_t off = 0;
    auto alloc = [&](size_t bytes) { void* r = p + off; off += align256(bytes); return r; };
    int*            flags   = (int*)alloc(256);
    int*            cnt     = (int*)alloc((size_t)NKEY * 4);
    int*            fill    = (int*)alloc((size_t)NKEY * 4);
    int*            keyptr  = (int*)alloc((size_t)(NKEY + 1) * 4);
    int*            bsum    = (int*)alloc((size_t)KB * 4);
    float*          dinv    = (float*)alloc((size_t)NN * 4);
    int*            col     = (int*)alloc((size_t)NE * 4);
    unsigned short* x0b     = (unsigned short*)alloc((size_t)NN * HD * 2);
    unsigned short* hA      = (unsigned short*)alloc((size_t)NN * HD * 2);
    unsigned short* hB      = (unsigned short*)alloc((size_t)NN * HD * 2);

    detect_kernel<<<1, 64, 0, stream>>>(x, eidx, flags);

    hipMemsetAsync(cnt, 0, (size_t)NKEY * 4, stream);
    hipMemsetAsync(fill, 0, (size_t)NKEY * 4, stream);
    key_count<<<(NE + 255) / 256, 256, 0, stream>>>(eidx, flags, cnt);
    scan_reduce<<<KB, 1024, 0, stream>>>(cnt, bsum);
    scan_mid<<<1, 1024, 0, stream>>>(bsum, keyptr + NKEY);
    scan_final<<<KB, 1024, 0, stream>>>(cnt, bsum, keyptr);
    dinv_kernel<<<(NN + 255) / 256, 256, 0, stream>>>(keyptr, dinv);
    scatter_kernel<<<(NE + 255) / 256, 256, 0, stream>>>(eidx, flags, keyptr, fill, col);

    int fb = (NN + RPB - 1) / RPB;  // 6250 blocks
    x0_kernel<<<fb, 256, 0, stream>>>(x, W1, b1, flags, dinv, x0b, hA);

    unsigned short* gin = hA;
    unsigned short* gout = hB;
    for (int l = 0; l < NL; l++) {
        float beta = logf(0.5f / (float)(l + 1) + 1.0f);
        layer_fused<<<fb, 256, 0, stream>>>(keyptr, col, dinv, gin, x0b, gout,
                                            convW, l, flags, beta);
        unsigned short* t = gin; gin = gout; gout = t;
    }
    out_kernel<<<(NN + 3) / 4, 256, 0, stream>>>(gin, dinv, W2, b2, flags, (void*)d_out);
}